// Round 7
// baseline (361.116 us; speedup 1.0000x reference)
//
#include <hip/hip_runtime.h>
#include <hip/hip_bf16.h>
#include <math.h>

#define BB   2
#define HWl  1024
#define DINO 768
#define COG  1920
#define NHh  12
#define TKV  4096
#define MQ   (BB*HWl)      // 2048
#define MKV  (BB*TKV)      // 8192
#define NSPL 4
#define ROWS_PER_SPLIT (BB*NHh*HWl)   // 24576

typedef __attribute__((ext_vector_type(8))) short bf16x8;
typedef __attribute__((ext_vector_type(4))) float f32x4;

__device__ __forceinline__ unsigned short f2bf_bits(float f) {
    __hip_bfloat16 h = __float2bfloat16(f);
    return *reinterpret_cast<unsigned short*>(&h);
}

__device__ __forceinline__ void glds16(const __hip_bfloat16* g, __hip_bfloat16* l) {
    __builtin_amdgcn_global_load_lds((const __attribute__((address_space(1))) void*)g,
                                     (__attribute__((address_space(3))) void*)l, 16, 0, 0);
}

// =================== prep mega-kernel ===================
// blocks [0,2048)        : LN of cog -> xkv bf16 (wave per row, 4 rows/block)
// blocks [2048,2080)     : dino NCHW transpose + LN -> xq bf16 (64 hw rows/block)
// blocks [2080,7840)     : weight transposes -> WqT, WkvT(concat), WoT
__global__ __launch_bounds__(256) void prep(const float* __restrict__ dino,
                                            const float* __restrict__ cog,
                                            const float* __restrict__ gq,  const float* __restrict__ Bq,
                                            const float* __restrict__ gkv, const float* __restrict__ Bkv,
                                            const float* __restrict__ Wq, const float* __restrict__ Wk,
                                            const float* __restrict__ Wv, const float* __restrict__ Wo,
                                            __hip_bfloat16* __restrict__ xq,
                                            __hip_bfloat16* __restrict__ xkv,
                                            __hip_bfloat16* WqT, __hip_bfloat16* WkvT, __hip_bfloat16* WoT) {
    int bid = blockIdx.x, tid = threadIdx.x;
    if (bid < 2048) {
        // ---- LN kv: W=1920, 8 float4 chunks per lane ----
        const int W = COG, W4 = W >> 2, NC = 8;
        int row = bid * 4 + (tid >> 6), lane = tid & 63;
        const float4* xr = (const float4*)(cog + (size_t)row * W);
        const float4* g4 = (const float4*)gkv;
        const float4* b4 = (const float4*)Bkv;
        float4 v[NC];
        float s = 0.f, ss = 0.f;
        #pragma unroll
        for (int i = 0; i < NC; ++i) {
            int c = lane + i * 64;
            float4 t = (c < W4) ? xr[c] : (float4){0.f, 0.f, 0.f, 0.f};
            v[i] = t;
            s  += t.x + t.y + t.z + t.w;
            ss += t.x * t.x + t.y * t.y + t.z * t.z + t.w * t.w;
        }
        #pragma unroll
        for (int off = 1; off < 64; off <<= 1) {
            s  += __shfl_xor(s, off);
            ss += __shfl_xor(ss, off);
        }
        float mu = s / W;
        float rstd = rsqrtf(ss / W - mu * mu + 1e-5f);
        ushort4* yr = (ushort4*)(xkv + (size_t)row * W);
        #pragma unroll
        for (int i = 0; i < NC; ++i) {
            int c = lane + i * 64;
            if (c < W4) {
                float4 t = v[i];
                float4 gg = g4[c], bb = b4[c];
                ushort4 o;
                o.x = f2bf_bits((t.x - mu) * rstd * gg.x + bb.x);
                o.y = f2bf_bits((t.y - mu) * rstd * gg.y + bb.y);
                o.z = f2bf_bits((t.z - mu) * rstd * gg.z + bb.z);
                o.w = f2bf_bits((t.w - mu) * rstd * gg.w + bb.w);
                yr[c] = o;
            }
        }
    } else if (bid < 2080) {
        // ---- dino transpose + LN: block = 64 hw rows of one batch ----
        int t = bid - 2048;
        int b = t >> 4, hw0 = (t & 15) << 6;
        int hw = tid & 63, cq = tid >> 6;        // cq 0..3
        const float* base = dino + (size_t)b * (DINO * HWl) + hw0 + hw;
        float s = 0.f, ss = 0.f;
        for (int c = cq; c < DINO; c += 4) {
            float v = base[(size_t)c * HWl];
            s += v; ss += v * v;
        }
        __shared__ float sred[4][64], ssred[4][64];
        sred[cq][hw] = s; ssred[cq][hw] = ss;
        __syncthreads();
        __shared__ float mu_s[64], rs_s[64];
        if (tid < 64) {
            float S  = sred[0][tid] + sred[1][tid] + sred[2][tid] + sred[3][tid];
            float SS = ssred[0][tid] + ssred[1][tid] + ssred[2][tid] + ssred[3][tid];
            float mu = S * (1.f / DINO);
            mu_s[tid] = mu;
            rs_s[tid] = rsqrtf(SS * (1.f / DINO) - mu * mu + 1e-5f);
        }
        __syncthreads();
        float mu = mu_s[hw], rs = rs_s[hw];
        __shared__ __hip_bfloat16 T2[64][68];
        for (int ch = 0; ch < 12; ++ch) {
            __syncthreads();
            #pragma unroll
            for (int i = 0; i < 16; ++i) {
                int cl = cq + 4 * i;
                int c = ch * 64 + cl;
                float v = base[(size_t)c * HWl];
                T2[hw][cl] = __float2bfloat16((v - mu) * rs * gq[c] + Bq[c]);
            }
            __syncthreads();
            int cl = (tid & 15) * 4;
            int hr = tid >> 4;
            #pragma unroll
            for (int ii = 0; ii < 4; ++ii) {
                int hwr = hr + ii * 16;
                *(ushort4*)(xq + (size_t)(b * HWl + hw0 + hwr) * DINO + ch * 64 + cl) =
                    *(ushort4*)&T2[hwr][cl];
            }
        }
    } else {
        // ---- weight transposes ----
        int bid2 = bid - 2080;
        int mid = bid2 / 1440, r = bid2 % 1440;
        int k0 = (r % 60) * 32, n0 = (r / 60) * 32;
        const float* src = (mid == 0) ? Wq : (mid == 1) ? Wk : (mid == 2) ? Wv : Wo;
        __hip_bfloat16* dst;
        int rowoff = 0;
        if (mid == 0) dst = WqT;
        else if (mid == 1) dst = WkvT;
        else if (mid == 2) { dst = WkvT; rowoff = 768; }
        else dst = WoT;
        int K = (mid == 1 || mid == 2) ? COG : DINO;
        if (k0 >= K) return;
        __shared__ float T[32][33];
        #pragma unroll
        for (int i = 0; i < 4; ++i) {
            int idx = tid + i * 256;
            int rr = idx >> 5, c = idx & 31;
            T[rr][c] = src[(size_t)(k0 + rr) * DINO + n0 + c];
        }
        __syncthreads();
        #pragma unroll
        for (int i = 0; i < 4; ++i) {
            int idx = tid + i * 256;
            int rr = idx >> 5, c = idx & 31;
            dst[(size_t)(rowoff + n0 + rr) * K + k0 + c] = __float2bfloat16(T[c][rr]);
        }
    }
}

// =================== stage1: fused KV GEMM + Q GEMM ===================
// blocks [0,768)   : KV: xkv[8192,1920] @ WkvT[1536,1920]^T; n<768->kb, n>=768->VT
// blocks [768,960) : Q:  xq[2048,768] @ WqT[768,768]^T -> qb
__global__ __launch_bounds__(256) void stage1(const __hip_bfloat16* __restrict__ xq,
                                              const __hip_bfloat16* __restrict__ WqT,
                                              const float* __restrict__ bq,
                                              __hip_bfloat16* __restrict__ qb,
                                              const __hip_bfloat16* __restrict__ xkv,
                                              const __hip_bfloat16* __restrict__ WkvT,
                                              const float* __restrict__ bk,
                                              const float* __restrict__ bv,
                                              __hip_bfloat16* __restrict__ kb,
                                              __hip_bfloat16* __restrict__ VT) {
    __shared__ __hip_bfloat16 SM[2 * 128 * 64];
    int bid = blockIdx.x;
    int tid = threadIdx.x, w = tid >> 6, lane = tid & 63;
    int l4 = lane & 15, lq = lane >> 4;
    int sws = l4 & 7;
    int rr = tid >> 3;
    int gcs = (tid & 7) ^ (rr & 7);

    if (bid < 768) {
        const int K = COG;
        __hip_bfloat16* As = SM;
        __hip_bfloat16* Bs = SM + 128 * 64;
        int m0 = (bid & 63) * 128, n0 = (bid >> 6) * 128;
        int mq = (w & 1) * 64, nq = (w >> 1) * 64;
        f32x4 acc[4][4];
        #pragma unroll
        for (int i = 0; i < 4; ++i)
            #pragma unroll
            for (int j = 0; j < 4; ++j) acc[i][j] = (f32x4){0.f, 0.f, 0.f, 0.f};

        const __hip_bfloat16* ag = xkv  + (size_t)(m0 + rr) * K + gcs * 8;
        const __hip_bfloat16* bg = WkvT + (size_t)(n0 + rr) * K + gcs * 8;
        __hip_bfloat16* asl = As + (w * 8) * 64;
        __hip_bfloat16* bsl = Bs + (w * 8) * 64;

        for (int k0 = 0; k0 < K; k0 += 64) {
            __syncthreads();
            #pragma unroll
            for (int g = 0; g < 4; ++g) {
                glds16(ag + (size_t)(g * 32) * K + k0, asl + g * 32 * 64);
                glds16(bg + (size_t)(g * 32) * K + k0, bsl + g * 32 * 64);
            }
            __syncthreads();
            #pragma unroll
            for (int h = 0; h < 2; ++h) {
                bf16x8 a[4], b[4];
                #pragma unroll
                for (int i = 0; i < 4; ++i)
                    a[i] = *(const bf16x8*)(As + (mq + 16 * i + l4) * 64 + (((h * 4 + lq) ^ sws) * 8));
                #pragma unroll
                for (int j = 0; j < 4; ++j)
                    b[j] = *(const bf16x8*)(Bs + (nq + 16 * j + l4) * 64 + (((h * 4 + lq) ^ sws) * 8));
                #pragma unroll
                for (int i = 0; i < 4; ++i)
                    #pragma unroll
                    for (int j = 0; j < 4; ++j)
                        acc[i][j] = __builtin_amdgcn_mfma_f32_16x16x32_bf16(a[i], b[j], acc[i][j], 0, 0, 0);
            }
        }

        if (n0 < 768) {
            #pragma unroll
            for (int i = 0; i < 4; ++i)
                #pragma unroll
                for (int j = 0; j < 4; ++j)
                    #pragma unroll
                    for (int r = 0; r < 4; ++r) {
                        int m = m0 + mq + 16 * i + lq * 4 + r;
                        int n = n0 + nq + 16 * j + l4;
                        kb[(size_t)m * DINO + n] = __float2bfloat16(acc[i][j][r] + bk[n]);
                    }
        } else {
            #pragma unroll
            for (int i = 0; i < 4; ++i)
                #pragma unroll
                for (int j = 0; j < 4; ++j)
                    #pragma unroll
                    for (int r = 0; r < 4; ++r) {
                        int m = m0 + mq + 16 * i + lq * 4 + r;
                        int n = n0 + nq + 16 * j + l4 - 768;
                        VT[((size_t)((m >> 12) * 768 + n)) * TKV + (m & 4095)] =
                            __float2bfloat16(acc[i][j][r] + bv[n]);
                    }
        }
    } else {
        const int K = DINO;
        __hip_bfloat16* As = SM;
        __hip_bfloat16* Bs = SM + 64 * 64;
        int bid2 = bid - 768;
        int m0 = (bid2 & 31) * 64, n0 = (bid2 >> 5) * 128;
        int mq = (w & 1) * 32, nq = (w >> 1) * 64;
        f32x4 acc[2][4];
        #pragma unroll
        for (int i = 0; i < 2; ++i)
            #pragma unroll
            for (int j = 0; j < 4; ++j) acc[i][j] = (f32x4){0.f, 0.f, 0.f, 0.f};

        const __hip_bfloat16* ag = xq  + (size_t)(m0 + rr) * K + gcs * 8;
        const __hip_bfloat16* bg = WqT + (size_t)(n0 + rr) * K + gcs * 8;
        __hip_bfloat16* asl = As + (w * 8) * 64;
        __hip_bfloat16* bsl = Bs + (w * 8) * 64;

        for (int k0 = 0; k0 < K; k0 += 64) {
            __syncthreads();
            #pragma unroll
            for (int g = 0; g < 2; ++g)
                glds16(ag + (size_t)(g * 32) * K + k0, asl + g * 32 * 64);
            #pragma unroll
            for (int g = 0; g < 4; ++g)
                glds16(bg + (size_t)(g * 32) * K + k0, bsl + g * 32 * 64);
            __syncthreads();
            #pragma unroll
            for (int h = 0; h < 2; ++h) {
                bf16x8 a[2], b[4];
                #pragma unroll
                for (int i = 0; i < 2; ++i)
                    a[i] = *(const bf16x8*)(As + (mq + 16 * i + l4) * 64 + (((h * 4 + lq) ^ sws) * 8));
                #pragma unroll
                for (int j = 0; j < 4; ++j)
                    b[j] = *(const bf16x8*)(Bs + (nq + 16 * j + l4) * 64 + (((h * 4 + lq) ^ sws) * 8));
                #pragma unroll
                for (int i = 0; i < 2; ++i)
                    #pragma unroll
                    for (int j = 0; j < 4; ++j)
                        acc[i][j] = __builtin_amdgcn_mfma_f32_16x16x32_bf16(a[i], b[j], acc[i][j], 0, 0, 0);
            }
        }
        #pragma unroll
        for (int i = 0; i < 2; ++i)
            #pragma unroll
            for (int j = 0; j < 4; ++j)
                #pragma unroll
                for (int r = 0; r < 4; ++r) {
                    int m = m0 + mq + 16 * i + lq * 4 + r;
                    int n = n0 + nq + 16 * j + l4;
                    qb[(size_t)m * DINO + n] = __float2bfloat16(acc[i][j][r] + bq[n]);
                }
    }
}

// =================== O projection (C^T epilogue -> NCHW fp32) ===================
__global__ __launch_bounds__(256) void gemm_o(const __hip_bfloat16* __restrict__ A,
                                              const __hip_bfloat16* __restrict__ Bt,
                                              const float* __restrict__ bias,
                                              float* __restrict__ out) {
    const int K = DINO;
    __shared__ __hip_bfloat16 As[64 * 64];
    __shared__ __hip_bfloat16 Bs[128 * 64];
    int m0 = blockIdx.x * 64, n0 = blockIdx.y * 128;
    int tid = threadIdx.x, w = tid >> 6, lane = tid & 63;
    int l4 = lane & 15, lq = lane >> 4;
    int mq = (w & 1) * 32, nq = (w >> 1) * 64;
    f32x4 acc[2][4];
    #pragma unroll
    for (int i = 0; i < 2; ++i)
        #pragma unroll
        for (int j = 0; j < 4; ++j) acc[i][j] = (f32x4){0.f, 0.f, 0.f, 0.f};

    int rr = tid >> 3;
    int gc = (tid & 7) ^ (rr & 7);
    const __hip_bfloat16* ag = A  + (size_t)(m0 + rr) * K + gc * 8;
    const __hip_bfloat16* bg = Bt + (size_t)(n0 + rr) * K + gc * 8;
    __hip_bfloat16* asl = As + (w * 8) * 64;
    __hip_bfloat16* bsl = Bs + (w * 8) * 64;
    int sws = l4 & 7;

    for (int k0 = 0; k0 < K; k0 += 64) {
        __syncthreads();
        #pragma unroll
        for (int g = 0; g < 2; ++g)
            glds16(ag + (size_t)(g * 32) * K + k0, asl + g * 32 * 64);
        #pragma unroll
        for (int g = 0; g < 4; ++g)
            glds16(bg + (size_t)(g * 32) * K + k0, bsl + g * 32 * 64);
        __syncthreads();
        #pragma unroll
        for (int h = 0; h < 2; ++h) {
            bf16x8 a[2], b[4];
            #pragma unroll
            for (int i = 0; i < 2; ++i)
                a[i] = *(const bf16x8*)(As + (mq + 16 * i + l4) * 64 + (((h * 4 + lq) ^ sws) * 8));
            #pragma unroll
            for (int j = 0; j < 4; ++j)
                b[j] = *(const bf16x8*)(Bs + (nq + 16 * j + l4) * 64 + (((h * 4 + lq) ^ sws) * 8));
            #pragma unroll
            for (int i = 0; i < 2; ++i)
                #pragma unroll
                for (int j = 0; j < 4; ++j)
                    acc[i][j] = __builtin_amdgcn_mfma_f32_16x16x32_bf16(b[j], a[i], acc[i][j], 0, 0, 0);
        }
    }
    #pragma unroll
    for (int i = 0; i < 2; ++i)
        #pragma unroll
        for (int j = 0; j < 4; ++j)
            #pragma unroll
            for (int r = 0; r < 4; ++r) {
                int n = n0 + nq + 16 * j + lq * 4 + r;
                int m = m0 + mq + 16 * i + l4;
                int b = m >> 10, hw = m & 1023;
                out[((size_t)b * DINO + n) * HWl + hw] = acc[i][j][r] + bias[n];
            }
}

// =================== flash attention (128-q tile, S^T MFMA, exp2) ===================
__global__ __launch_bounds__(256) void attn3(const __hip_bfloat16* __restrict__ qb,
                                             const __hip_bfloat16* __restrict__ kb,
                                             const __hip_bfloat16* __restrict__ VT,
                                             const float* __restrict__ tw,
                                             float* __restrict__ Opart,
                                             float* __restrict__ lpart) {
    int bid = blockIdx.x;
    int g = bid % 96, qc = bid / 96;
    int s = g & 3, bh = g >> 2;
    int head = bh % NHh, b = bh / NHh;
    int tid = threadIdx.x, w = tid >> 6, lane = tid & 63;
    int l4 = lane & 15, lq = lane >> 4;

    __shared__ __hip_bfloat16 Ks[64 * 64];
    __shared__ __hip_bfloat16 Vs[64 * 64];
    __shared__ __hip_bfloat16 Ps[4 * 32 * 64];

    const __hip_bfloat16* qbase = qb + (size_t)(b * HWl + qc * 128 + w * 32 + l4) * DINO + head * 64;
    bf16x8 qA0 = *(const bf16x8*)(qbase + lq * 8);
    bf16x8 qA1 = *(const bf16x8*)(qbase + 32 + lq * 8);
    const __hip_bfloat16* qbase2 = qbase + (size_t)16 * DINO;
    bf16x8 qB0 = *(const bf16x8*)(qbase2 + lq * 8);
    bf16x8 qB1 = *(const bf16x8*)(qbase2 + 32 + lq * 8);

    float c = tw[s] * 0.125f * 1.44269504f;
    float l_iA = 0.f, l_iB = 0.f;
    f32x4 oA[4], oB[4];
    #pragma unroll
    for (int j = 0; j < 4; ++j) { oA[j] = (f32x4){0.f,0.f,0.f,0.f}; oB[j] = (f32x4){0.f,0.f,0.f,0.f}; }

    int rowA = w * 16 + (lane >> 3);
    int cg = (lane & 7) ^ ((lane >> 3) & 7);
    const __hip_bfloat16* kg0 = kb + (size_t)(b * TKV + s * 1024 + rowA) * DINO + head * 64 + cg * 8;
    const __hip_bfloat16* kg1 = kg0 + (size_t)8 * DINO;
    const __hip_bfloat16* vg0 = VT + (size_t)(b * 768 + head * 64 + rowA) * TKV + s * 1024 + cg * 8;
    const __hip_bfloat16* vg1 = vg0 + (size_t)8 * TKV;
    __hip_bfloat16* kl0 = Ks + (w * 2 + 0) * 512;
    __hip_bfloat16* kl1 = Ks + (w * 2 + 1) * 512;
    __hip_bfloat16* vl0 = Vs + (w * 2 + 0) * 512;
    __hip_bfloat16* vl1 = Vs + (w * 2 + 1) * 512;

    int sw0 = (lq ^ (l4 & 7)) * 8;
    int sw1 = ((4 + lq) ^ (l4 & 7)) * 8;
    __hip_bfloat16* PsA = Ps + w * 2048 + l4 * 64;
    __hip_bfloat16* PsB = Ps + w * 2048 + (16 + l4) * 64;

    for (int kt = 0; kt < 16; ++kt) {
        __syncthreads();
        glds16(kg0 + (size_t)kt * 64 * DINO, kl0);
        glds16(kg1 + (size_t)kt * 64 * DINO, kl1);
        glds16(vg0 + kt * 64, vl0);
        glds16(vg1 + kt * 64, vl1);
        __syncthreads();

        f32x4 stA[4], stB[4];
        #pragma unroll
        for (int j = 0; j < 4; ++j) {
            const __hip_bfloat16* kr = Ks + (16 * j + l4) * 64;
            bf16x8 kf0 = *(const bf16x8*)(kr + sw0);
            bf16x8 kf1 = *(const bf16x8*)(kr + sw1);
            f32x4 a = (f32x4){0.f,0.f,0.f,0.f};
            a = __builtin_amdgcn_mfma_f32_16x16x32_bf16(kf0, qA0, a, 0, 0, 0);
            a = __builtin_amdgcn_mfma_f32_16x16x32_bf16(kf1, qA1, a, 0, 0, 0);
            stA[j] = a;
            f32x4 bb = (f32x4){0.f,0.f,0.f,0.f};
            bb = __builtin_amdgcn_mfma_f32_16x16x32_bf16(kf0, qB0, bb, 0, 0, 0);
            bb = __builtin_amdgcn_mfma_f32_16x16x32_bf16(kf1, qB1, bb, 0, 0, 0);
            stB[j] = bb;
        }

        float lsA = 0.f, lsB = 0.f;
        #pragma unroll
        for (int j = 0; j < 4; ++j)
            #pragma unroll
            for (int r = 0; r < 4; ++r) {
                float eA = exp2f(stA[j][r] * c);
                float eB = exp2f(stB[j][r] * c);
                stA[j][r] = eA; lsA += eA;
                stB[j][r] = eB; lsB += eB;
            }
        lsA += __shfl_xor(lsA, 16); lsA += __shfl_xor(lsA, 32);
        lsB += __shfl_xor(lsB, 16); lsB += __shfl_xor(lsB, 32);
        l_iA += lsA; l_iB += lsB;

        #pragma unroll
        for (int j = 0; j < 4; ++j) {
            int off = (((2 * j + (lq >> 1)) ^ (l4 & 7)) << 3) + (lq & 1) * 4;
            ushort4 pA, pB;
            pA.x = f2bf_bits(stA[j][0]); pA.y = f2bf_bits(stA[j][1]);
            pA.z = f2bf_bits(stA[j][2]); pA.w = f2bf_bits(stA[j][3]);
            pB.x = f2bf_bits(stB[j][0]); pB.y = f2bf_bits(stB[j][1]);
            pB.z = f2bf_bits(stB[j][2]); pB.w = f2bf_bits(stB[j][3]);
            *(ushort4*)&PsA[off] = pA;
            *(ushort4*)&PsB[off] = pB;
        }
        bf16x8 paA0 = *(const bf16x8*)(PsA + sw0);
        bf16x8 paA1 = *(const bf16x8*)(PsA + sw1);
        bf16x8 paB0 = *(const bf16x8*)(PsB + sw0);
        bf16x8 paB1 = *(const bf16x8*)(PsB + sw1);

        #pragma unroll
        for (int j = 0; j < 4; ++j) {
            const __hip_bfloat16* vr = Vs + (16 * j + l4) * 64;
            bf16x8 vf0 = *(const bf16x8*)(vr + sw0);
            bf16x8 vf1 = *(const bf16x8*)(vr + sw1);
            oA[j] = __builtin_amdgcn_mfma_f32_16x16x32_bf16(paA0, vf0, oA[j], 0, 0, 0);
            oA[j] = __builtin_amdgcn_mfma_f32_16x16x32_bf16(paA1, vf1, oA[j], 0, 0, 0);
            oB[j] = __builtin_amdgcn_mfma_f32_16x16x32_bf16(paB0, vf0, oB[j], 0, 0, 0);
            oB[j] = __builtin_amdgcn_mfma_f32_16x16x32_bf16(paB1, vf1, oB[j], 0, 0, 0);
        }
    }

    size_t rb = (size_t)s * ROWS_PER_SPLIT + (size_t)(b * NHh + head) * HWl + qc * 128 + w * 32;
    #pragma unroll
    for (int j = 0; j < 4; ++j)
        #pragma unroll
        for (int r = 0; r < 4; ++r) {
            Opart[(rb + lq * 4 + r) * 64 + j * 16 + l4]      = oA[j][r];
            Opart[(rb + 16 + lq * 4 + r) * 64 + j * 16 + l4] = oB[j][r];
        }
    if (lq == 0) {
        lpart[rb + l4]      = l_iA;
        lpart[rb + 16 + l4] = l_iB;
    }
}

// =================== combine split partials ===================
__global__ void combine(const float* __restrict__ Opart, const float* __restrict__ lpart,
                        __hip_bfloat16* __restrict__ attn) {
    int p = blockIdx.x * 4 + (threadIdx.x >> 6);
    int d = threadIdx.x & 63;
    float L = 0.f, O = 0.f;
    #pragma unroll
    for (int s = 0; s < NSPL; ++s) {
        L += lpart[(size_t)s * ROWS_PER_SPLIT + p];
        O += Opart[((size_t)s * ROWS_PER_SPLIT + p) * 64 + d];
    }
    float res = O / L;
    int q = p & 1023;
    int bh = p >> 10;
    int head = bh % NHh, b = bh / NHh;
    attn[((size_t)(b * HWl + q)) * DINO + head * 64 + d] = __float2bfloat16(res);
}

// =================== launch ===================
extern "C" void kernel_launch(void* const* d_in, const int* in_sizes, int n_in,
                              void* d_out, int out_size, void* d_ws, size_t ws_size,
                              hipStream_t stream) {
    (void)in_sizes; (void)n_in; (void)out_size; (void)ws_size;
    const float* dino = (const float*)d_in[0];
    const float* cog  = (const float*)d_in[1];
    const float* tw   = (const float*)d_in[2];
    const float* Wq   = (const float*)d_in[3];
    const float* bq   = (const float*)d_in[4];
    const float* Wk   = (const float*)d_in[5];
    const float* bk   = (const float*)d_in[6];
    const float* Wv   = (const float*)d_in[7];
    const float* bv   = (const float*)d_in[8];
    const float* Wo   = (const float*)d_in[9];
    const float* bo   = (const float*)d_in[10];
    const float* gq   = (const float*)d_in[11];
    const float* Bq   = (const float*)d_in[12];
    const float* gkv  = (const float*)d_in[13];
    const float* Bkv  = (const float*)d_in[14];

    char* p = (char*)d_ws;
    __hip_bfloat16* xq = (__hip_bfloat16*)p;   p += (size_t)MQ * DINO * 2;
    char* alias = p;                           p += (size_t)MKV * COG * 2;   // xkv | Opart+lpart
    __hip_bfloat16* xkv = (__hip_bfloat16*)alias;
    __hip_bfloat16* WqT  = (__hip_bfloat16*)p; p += (size_t)DINO * DINO * 2;
    __hip_bfloat16* WkvT = (__hip_bfloat16*)p; p += (size_t)1536 * COG * 2;
    __hip_bfloat16* WoT  = (__hip_bfloat16*)p; p += (size_t)DINO * DINO * 2;
    __hip_bfloat16* qb   = (__hip_bfloat16*)p; p += (size_t)MQ  * DINO * 2;
    __hip_bfloat16* kb   = (__hip_bfloat16*)p; p += (size_t)MKV * DINO * 2;
    __hip_bfloat16* VT   = (__hip_bfloat16*)p; p += (size_t)MKV * DINO * 2;
    __hip_bfloat16* attnb = (__hip_bfloat16*)p; p += (size_t)MQ * DINO * 2;
    float* Opart = (float*)alias;
    float* lpart = (float*)(alias + (size_t)NSPL * ROWS_PER_SPLIT * 64 * 4);

    prep<<<7840, 256, 0, stream>>>(dino, cog, gq, Bq, gkv, Bkv,
                                   Wq, Wk, Wv, Wo, xq, xkv, WqT, WkvT, WoT);
    stage1<<<960, 256, 0, stream>>>(xq, WqT, bq, qb, xkv, WkvT, bk, bv, kb, VT);
    attn3<<<BB * NHh * 8 * NSPL, 256, 0, stream>>>(qb, kb, VT, tw, Opart, lpart);
    combine<<<ROWS_PER_SPLIT / 4, 256, 0, stream>>>(Opart, lpart, attnb);
    gemm_o<<<dim3(32, 6), 256, 0, stream>>>(attnb, WoT, bo, (float*)d_out);
}

// Round 8
// 278.746 us; speedup vs baseline: 1.2955x; 1.2955x over previous
//
#include <hip/hip_runtime.h>
#include <hip/hip_bf16.h>
#include <math.h>

#define BB   2
#define HWl  1024
#define DINO 768
#define COG  1920
#define NHh  12
#define TKV  4096
#define MQ   (BB*HWl)      // 2048
#define MKV  (BB*TKV)      // 8192
#define NSPL 4
#define ROWS_PER_SPLIT (BB*NHh*HWl)   // 24576

typedef __attribute__((ext_vector_type(8))) short bf16x8;
typedef __attribute__((ext_vector_type(4))) float f32x4;

__device__ __forceinline__ unsigned short f2bf_bits(float f) {
    __hip_bfloat16 h = __float2bfloat16(f);
    return *reinterpret_cast<unsigned short*>(&h);
}

__device__ __forceinline__ void glds16(const __hip_bfloat16* g, __hip_bfloat16* l) {
    __builtin_amdgcn_global_load_lds((const __attribute__((address_space(1))) void*)g,
                                     (__attribute__((address_space(3))) void*)l, 16, 0, 0);
}

// =================== prep1 mega-kernel ===================
// blocks [0,2048)     : LN of cog -> xkv bf16 (wave per row, 4 rows/block)
// blocks [2048,2432)  : dino NCHW -> xqT fp32 transpose (64x64 LDS tiles, coalesced)
// blocks [2432,8192)  : weight transposes -> WqT, WkvT(concat), WoT
__global__ __launch_bounds__(256) void prep1(const float* __restrict__ dino,
                                             const float* __restrict__ cog,
                                             const float* __restrict__ gkv, const float* __restrict__ Bkv,
                                             const float* __restrict__ Wq, const float* __restrict__ Wk,
                                             const float* __restrict__ Wv, const float* __restrict__ Wo,
                                             float* __restrict__ xqT,
                                             __hip_bfloat16* __restrict__ xkv,
                                             __hip_bfloat16* WqT, __hip_bfloat16* WkvT, __hip_bfloat16* WoT) {
    int bid = blockIdx.x, tid = threadIdx.x;
    if (bid < 2048) {
        // ---- LN kv: W=1920, 8 float4 chunks per lane ----
        const int W = COG, W4 = W >> 2, NC = 8;
        int row = bid * 4 + (tid >> 6), lane = tid & 63;
        const float4* xr = (const float4*)(cog + (size_t)row * W);
        const float4* g4 = (const float4*)gkv;
        const float4* b4 = (const float4*)Bkv;
        float4 v[NC];
        float s = 0.f, ss = 0.f;
        #pragma unroll
        for (int i = 0; i < NC; ++i) {
            int c = lane + i * 64;
            float4 t = (c < W4) ? xr[c] : (float4){0.f, 0.f, 0.f, 0.f};
            v[i] = t;
            s  += t.x + t.y + t.z + t.w;
            ss += t.x * t.x + t.y * t.y + t.z * t.z + t.w * t.w;
        }
        #pragma unroll
        for (int off = 1; off < 64; off <<= 1) {
            s  += __shfl_xor(s, off);
            ss += __shfl_xor(ss, off);
        }
        float mu = s / W;
        float rstd = rsqrtf(ss / W - mu * mu + 1e-5f);
        ushort4* yr = (ushort4*)(xkv + (size_t)row * W);
        #pragma unroll
        for (int i = 0; i < NC; ++i) {
            int c = lane + i * 64;
            if (c < W4) {
                float4 t = v[i];
                float4 gg = g4[c], bb = b4[c];
                ushort4 o;
                o.x = f2bf_bits((t.x - mu) * rstd * gg.x + bb.x);
                o.y = f2bf_bits((t.y - mu) * rstd * gg.y + bb.y);
                o.z = f2bf_bits((t.z - mu) * rstd * gg.z + bb.z);
                o.w = f2bf_bits((t.w - mu) * rstd * gg.w + bb.w);
                yr[c] = o;
            }
        }
    } else if (bid < 2432) {
        // ---- dino transpose: [B,768,HW] -> xqT [B*HW,768] fp32 ----
        int t = bid - 2048;                 // 384 = 16 x 12 x 2
        int h0 = (t & 15) * 64;
        int c0 = ((t >> 4) % 12) * 64;
        int b = t / 192;
        __shared__ float T[64][65];
        #pragma unroll
        for (int i = 0; i < 16; ++i) {
            int idx = tid + i * 256;
            int c = idx >> 6, h = idx & 63;
            T[c][h] = dino[((size_t)b * DINO + c0 + c) * HWl + h0 + h];
        }
        __syncthreads();
        #pragma unroll
        for (int i = 0; i < 16; ++i) {
            int idx = tid + i * 256;
            int r = idx >> 6, c = idx & 63;
            xqT[((size_t)b * HWl + h0 + r) * DINO + c0 + c] = T[c][r];
        }
    } else {
        // ---- weight transposes ----
        int bid2 = bid - 2432;
        int mid = bid2 / 1440, r = bid2 % 1440;
        int k0 = (r % 60) * 32, n0 = (r / 60) * 32;
        const float* src = (mid == 0) ? Wq : (mid == 1) ? Wk : (mid == 2) ? Wv : Wo;
        __hip_bfloat16* dst;
        int rowoff = 0;
        if (mid == 0) dst = WqT;
        else if (mid == 1) dst = WkvT;
        else if (mid == 2) { dst = WkvT; rowoff = 768; }
        else dst = WoT;
        int K = (mid == 1 || mid == 2) ? COG : DINO;
        if (k0 >= K) return;
        __shared__ float T[32][33];
        #pragma unroll
        for (int i = 0; i < 4; ++i) {
            int idx = tid + i * 256;
            int rr = idx >> 5, c = idx & 31;
            T[rr][c] = src[(size_t)(k0 + rr) * DINO + n0 + c];
        }
        __syncthreads();
        #pragma unroll
        for (int i = 0; i < 4; ++i) {
            int idx = tid + i * 256;
            int rr = idx >> 5, c = idx & 31;
            dst[(size_t)(rowoff + n0 + rr) * K + k0 + c] = __float2bfloat16(T[c][rr]);
        }
    }
}

// =================== prep2: LN of xqT rows -> xq bf16 ===================
__global__ __launch_bounds__(256) void prep2(const float* __restrict__ x,
                                             const float* __restrict__ g,
                                             const float* __restrict__ be,
                                             __hip_bfloat16* __restrict__ y) {
    const int W = DINO, W4 = W >> 2, NC = 3;
    int row = blockIdx.x * 4 + (threadIdx.x >> 6);
    int lane = threadIdx.x & 63;
    const float4* xr = (const float4*)(x + (size_t)row * W);
    const float4* g4 = (const float4*)g;
    const float4* b4 = (const float4*)be;
    float4 v[NC];
    float s = 0.f, ss = 0.f;
    #pragma unroll
    for (int i = 0; i < NC; ++i) {
        int c = lane + i * 64;
        float4 t = xr[c];
        v[i] = t;
        s  += t.x + t.y + t.z + t.w;
        ss += t.x * t.x + t.y * t.y + t.z * t.z + t.w * t.w;
    }
    #pragma unroll
    for (int off = 1; off < 64; off <<= 1) {
        s  += __shfl_xor(s, off);
        ss += __shfl_xor(ss, off);
    }
    float mu = s / W;
    float rstd = rsqrtf(ss / W - mu * mu + 1e-5f);
    ushort4* yr = (ushort4*)(y + (size_t)row * W);
    #pragma unroll
    for (int i = 0; i < NC; ++i) {
        int c = lane + i * 64;
        float4 t = v[i];
        float4 gg = g4[c], bb = b4[c];
        ushort4 o;
        o.x = f2bf_bits((t.x - mu) * rstd * gg.x + bb.x);
        o.y = f2bf_bits((t.y - mu) * rstd * gg.y + bb.y);
        o.z = f2bf_bits((t.z - mu) * rstd * gg.z + bb.z);
        o.w = f2bf_bits((t.w - mu) * rstd * gg.w + bb.w);
        yr[c] = o;
    }
}

// =================== stage1: fused KV GEMM + Q GEMM ===================
// blocks [0,768)   : KV: xkv[8192,1920] @ WkvT[1536,1920]^T; n<768->kb, n>=768->VT
// blocks [768,960) : Q:  xq[2048,768] @ WqT[768,768]^T -> qb
__global__ __launch_bounds__(256) void stage1(const __hip_bfloat16* __restrict__ xq,
                                              const __hip_bfloat16* __restrict__ WqT,
                                              const float* __restrict__ bq,
                                              __hip_bfloat16* __restrict__ qb,
                                              const __hip_bfloat16* __restrict__ xkv,
                                              const __hip_bfloat16* __restrict__ WkvT,
                                              const float* __restrict__ bk,
                                              const float* __restrict__ bv,
                                              __hip_bfloat16* __restrict__ kb,
                                              __hip_bfloat16* __restrict__ VT) {
    __shared__ __hip_bfloat16 SM[2 * 128 * 64];
    int bid = blockIdx.x;
    int tid = threadIdx.x, w = tid >> 6, lane = tid & 63;
    int l4 = lane & 15, lq = lane >> 4;
    int sws = l4 & 7;
    int rr = tid >> 3;
    int gcs = (tid & 7) ^ (rr & 7);

    if (bid < 768) {
        const int K = COG;
        __hip_bfloat16* As = SM;
        __hip_bfloat16* Bs = SM + 128 * 64;
        int m0 = (bid & 63) * 128, n0 = (bid >> 6) * 128;
        int mq = (w & 1) * 64, nq = (w >> 1) * 64;
        f32x4 acc[4][4];
        #pragma unroll
        for (int i = 0; i < 4; ++i)
            #pragma unroll
            for (int j = 0; j < 4; ++j) acc[i][j] = (f32x4){0.f, 0.f, 0.f, 0.f};

        const __hip_bfloat16* ag = xkv  + (size_t)(m0 + rr) * K + gcs * 8;
        const __hip_bfloat16* bg = WkvT + (size_t)(n0 + rr) * K + gcs * 8;
        __hip_bfloat16* asl = As + (w * 8) * 64;
        __hip_bfloat16* bsl = Bs + (w * 8) * 64;

        for (int k0 = 0; k0 < K; k0 += 64) {
            __syncthreads();
            #pragma unroll
            for (int g = 0; g < 4; ++g) {
                glds16(ag + (size_t)(g * 32) * K + k0, asl + g * 32 * 64);
                glds16(bg + (size_t)(g * 32) * K + k0, bsl + g * 32 * 64);
            }
            __syncthreads();
            #pragma unroll
            for (int h = 0; h < 2; ++h) {
                bf16x8 a[4], b[4];
                #pragma unroll
                for (int i = 0; i < 4; ++i)
                    a[i] = *(const bf16x8*)(As + (mq + 16 * i + l4) * 64 + (((h * 4 + lq) ^ sws) * 8));
                #pragma unroll
                for (int j = 0; j < 4; ++j)
                    b[j] = *(const bf16x8*)(Bs + (nq + 16 * j + l4) * 64 + (((h * 4 + lq) ^ sws) * 8));
                #pragma unroll
                for (int i = 0; i < 4; ++i)
                    #pragma unroll
                    for (int j = 0; j < 4; ++j)
                        acc[i][j] = __builtin_amdgcn_mfma_f32_16x16x32_bf16(a[i], b[j], acc[i][j], 0, 0, 0);
            }
        }

        if (n0 < 768) {
            #pragma unroll
            for (int i = 0; i < 4; ++i)
                #pragma unroll
                for (int j = 0; j < 4; ++j)
                    #pragma unroll
                    for (int r = 0; r < 4; ++r) {
                        int m = m0 + mq + 16 * i + lq * 4 + r;
                        int n = n0 + nq + 16 * j + l4;
                        kb[(size_t)m * DINO + n] = __float2bfloat16(acc[i][j][r] + bk[n]);
                    }
        } else {
            #pragma unroll
            for (int i = 0; i < 4; ++i)
                #pragma unroll
                for (int j = 0; j < 4; ++j)
                    #pragma unroll
                    for (int r = 0; r < 4; ++r) {
                        int m = m0 + mq + 16 * i + lq * 4 + r;
                        int n = n0 + nq + 16 * j + l4 - 768;
                        VT[((size_t)((m >> 12) * 768 + n)) * TKV + (m & 4095)] =
                            __float2bfloat16(acc[i][j][r] + bv[n]);
                    }
        }
    } else {
        const int K = DINO;
        __hip_bfloat16* As = SM;
        __hip_bfloat16* Bs = SM + 64 * 64;
        int bid2 = bid - 768;
        int m0 = (bid2 & 31) * 64, n0 = (bid2 >> 5) * 128;
        int mq = (w & 1) * 32, nq = (w >> 1) * 64;
        f32x4 acc[2][4];
        #pragma unroll
        for (int i = 0; i < 2; ++i)
            #pragma unroll
            for (int j = 0; j < 4; ++j) acc[i][j] = (f32x4){0.f, 0.f, 0.f, 0.f};

        const __hip_bfloat16* ag = xq  + (size_t)(m0 + rr) * K + gcs * 8;
        const __hip_bfloat16* bg = WqT + (size_t)(n0 + rr) * K + gcs * 8;
        __hip_bfloat16* asl = As + (w * 8) * 64;
        __hip_bfloat16* bsl = Bs + (w * 8) * 64;

        for (int k0 = 0; k0 < K; k0 += 64) {
            __syncthreads();
            #pragma unroll
            for (int g = 0; g < 2; ++g)
                glds16(ag + (size_t)(g * 32) * K + k0, asl + g * 32 * 64);
            #pragma unroll
            for (int g = 0; g < 4; ++g)
                glds16(bg + (size_t)(g * 32) * K + k0, bsl + g * 32 * 64);
            __syncthreads();
            #pragma unroll
            for (int h = 0; h < 2; ++h) {
                bf16x8 a[2], b[4];
                #pragma unroll
                for (int i = 0; i < 2; ++i)
                    a[i] = *(const bf16x8*)(As + (mq + 16 * i + l4) * 64 + (((h * 4 + lq) ^ sws) * 8));
                #pragma unroll
                for (int j = 0; j < 4; ++j)
                    b[j] = *(const bf16x8*)(Bs + (nq + 16 * j + l4) * 64 + (((h * 4 + lq) ^ sws) * 8));
                #pragma unroll
                for (int i = 0; i < 2; ++i)
                    #pragma unroll
                    for (int j = 0; j < 4; ++j)
                        acc[i][j] = __builtin_amdgcn_mfma_f32_16x16x32_bf16(a[i], b[j], acc[i][j], 0, 0, 0);
            }
        }
        #pragma unroll
        for (int i = 0; i < 2; ++i)
            #pragma unroll
            for (int j = 0; j < 4; ++j)
                #pragma unroll
                for (int r = 0; r < 4; ++r) {
                    int m = m0 + mq + 16 * i + lq * 4 + r;
                    int n = n0 + nq + 16 * j + l4;
                    qb[(size_t)m * DINO + n] = __float2bfloat16(acc[i][j][r] + bq[n]);
                }
    }
}

// =================== O projection (C^T epilogue -> NCHW fp32) ===================
__global__ __launch_bounds__(256) void gemm_o(const __hip_bfloat16* __restrict__ A,
                                              const __hip_bfloat16* __restrict__ Bt,
                                              const float* __restrict__ bias,
                                              float* __restrict__ out) {
    const int K = DINO;
    __shared__ __hip_bfloat16 As[64 * 64];
    __shared__ __hip_bfloat16 Bs[128 * 64];
    int m0 = blockIdx.x * 64, n0 = blockIdx.y * 128;
    int tid = threadIdx.x, w = tid >> 6, lane = tid & 63;
    int l4 = lane & 15, lq = lane >> 4;
    int mq = (w & 1) * 32, nq = (w >> 1) * 64;
    f32x4 acc[2][4];
    #pragma unroll
    for (int i = 0; i < 2; ++i)
        #pragma unroll
        for (int j = 0; j < 4; ++j) acc[i][j] = (f32x4){0.f, 0.f, 0.f, 0.f};

    int rr = tid >> 3;
    int gc = (tid & 7) ^ (rr & 7);
    const __hip_bfloat16* ag = A  + (size_t)(m0 + rr) * K + gc * 8;
    const __hip_bfloat16* bg = Bt + (size_t)(n0 + rr) * K + gc * 8;
    __hip_bfloat16* asl = As + (w * 8) * 64;
    __hip_bfloat16* bsl = Bs + (w * 8) * 64;
    int sws = l4 & 7;

    for (int k0 = 0; k0 < K; k0 += 64) {
        __syncthreads();
        #pragma unroll
        for (int g = 0; g < 2; ++g)
            glds16(ag + (size_t)(g * 32) * K + k0, asl + g * 32 * 64);
        #pragma unroll
        for (int g = 0; g < 4; ++g)
            glds16(bg + (size_t)(g * 32) * K + k0, bsl + g * 32 * 64);
        __syncthreads();
        #pragma unroll
        for (int h = 0; h < 2; ++h) {
            bf16x8 a[2], b[4];
            #pragma unroll
            for (int i = 0; i < 2; ++i)
                a[i] = *(const bf16x8*)(As + (mq + 16 * i + l4) * 64 + (((h * 4 + lq) ^ sws) * 8));
            #pragma unroll
            for (int j = 0; j < 4; ++j)
                b[j] = *(const bf16x8*)(Bs + (nq + 16 * j + l4) * 64 + (((h * 4 + lq) ^ sws) * 8));
            #pragma unroll
            for (int i = 0; i < 2; ++i)
                #pragma unroll
                for (int j = 0; j < 4; ++j)
                    acc[i][j] = __builtin_amdgcn_mfma_f32_16x16x32_bf16(b[j], a[i], acc[i][j], 0, 0, 0);
        }
    }
    #pragma unroll
    for (int i = 0; i < 2; ++i)
        #pragma unroll
        for (int j = 0; j < 4; ++j)
            #pragma unroll
            for (int r = 0; r < 4; ++r) {
                int n = n0 + nq + 16 * j + lq * 4 + r;
                int m = m0 + mq + 16 * i + l4;
                int b = m >> 10, hw = m & 1023;
                out[((size_t)b * DINO + n) * HWl + hw] = acc[i][j][r] + bias[n];
            }
}

// =================== flash attention (128-q tile, S^T MFMA, exp2) ===================
__global__ __launch_bounds__(256) void attn3(const __hip_bfloat16* __restrict__ qb,
                                             const __hip_bfloat16* __restrict__ kb,
                                             const __hip_bfloat16* __restrict__ VT,
                                             const float* __restrict__ tw,
                                             float* __restrict__ Opart,
                                             float* __restrict__ lpart) {
    int bid = blockIdx.x;
    int g = bid % 96, qc = bid / 96;
    int s = g & 3, bh = g >> 2;
    int head = bh % NHh, b = bh / NHh;
    int tid = threadIdx.x, w = tid >> 6, lane = tid & 63;
    int l4 = lane & 15, lq = lane >> 4;

    __shared__ __hip_bfloat16 Ks[64 * 64];
    __shared__ __hip_bfloat16 Vs[64 * 64];
    __shared__ __hip_bfloat16 Ps[4 * 32 * 64];

    const __hip_bfloat16* qbase = qb + (size_t)(b * HWl + qc * 128 + w * 32 + l4) * DINO + head * 64;
    bf16x8 qA0 = *(const bf16x8*)(qbase + lq * 8);
    bf16x8 qA1 = *(const bf16x8*)(qbase + 32 + lq * 8);
    const __hip_bfloat16* qbase2 = qbase + (size_t)16 * DINO;
    bf16x8 qB0 = *(const bf16x8*)(qbase2 + lq * 8);
    bf16x8 qB1 = *(const bf16x8*)(qbase2 + 32 + lq * 8);

    float c = tw[s] * 0.125f * 1.44269504f;
    float l_iA = 0.f, l_iB = 0.f;
    f32x4 oA[4], oB[4];
    #pragma unroll
    for (int j = 0; j < 4; ++j) { oA[j] = (f32x4){0.f,0.f,0.f,0.f}; oB[j] = (f32x4){0.f,0.f,0.f,0.f}; }

    int rowA = w * 16 + (lane >> 3);
    int cg = (lane & 7) ^ ((lane >> 3) & 7);
    const __hip_bfloat16* kg0 = kb + (size_t)(b * TKV + s * 1024 + rowA) * DINO + head * 64 + cg * 8;
    const __hip_bfloat16* kg1 = kg0 + (size_t)8 * DINO;
    const __hip_bfloat16* vg0 = VT + (size_t)(b * 768 + head * 64 + rowA) * TKV + s * 1024 + cg * 8;
    const __hip_bfloat16* vg1 = vg0 + (size_t)8 * TKV;
    __hip_bfloat16* kl0 = Ks + (w * 2 + 0) * 512;
    __hip_bfloat16* kl1 = Ks + (w * 2 + 1) * 512;
    __hip_bfloat16* vl0 = Vs + (w * 2 + 0) * 512;
    __hip_bfloat16* vl1 = Vs + (w * 2 + 1) * 512;

    int sw0 = (lq ^ (l4 & 7)) * 8;
    int sw1 = ((4 + lq) ^ (l4 & 7)) * 8;
    __hip_bfloat16* PsA = Ps + w * 2048 + l4 * 64;
    __hip_bfloat16* PsB = Ps + w * 2048 + (16 + l4) * 64;

    for (int kt = 0; kt < 16; ++kt) {
        __syncthreads();
        glds16(kg0 + (size_t)kt * 64 * DINO, kl0);
        glds16(kg1 + (size_t)kt * 64 * DINO, kl1);
        glds16(vg0 + kt * 64, vl0);
        glds16(vg1 + kt * 64, vl1);
        __syncthreads();

        f32x4 stA[4], stB[4];
        #pragma unroll
        for (int j = 0; j < 4; ++j) {
            const __hip_bfloat16* kr = Ks + (16 * j + l4) * 64;
            bf16x8 kf0 = *(const bf16x8*)(kr + sw0);
            bf16x8 kf1 = *(const bf16x8*)(kr + sw1);
            f32x4 a = (f32x4){0.f,0.f,0.f,0.f};
            a = __builtin_amdgcn_mfma_f32_16x16x32_bf16(kf0, qA0, a, 0, 0, 0);
            a = __builtin_amdgcn_mfma_f32_16x16x32_bf16(kf1, qA1, a, 0, 0, 0);
            stA[j] = a;
            f32x4 bb = (f32x4){0.f,0.f,0.f,0.f};
            bb = __builtin_amdgcn_mfma_f32_16x16x32_bf16(kf0, qB0, bb, 0, 0, 0);
            bb = __builtin_amdgcn_mfma_f32_16x16x32_bf16(kf1, qB1, bb, 0, 0, 0);
            stB[j] = bb;
        }

        float lsA = 0.f, lsB = 0.f;
        #pragma unroll
        for (int j = 0; j < 4; ++j)
            #pragma unroll
            for (int r = 0; r < 4; ++r) {
                float eA = exp2f(stA[j][r] * c);
                float eB = exp2f(stB[j][r] * c);
                stA[j][r] = eA; lsA += eA;
                stB[j][r] = eB; lsB += eB;
            }
        lsA += __shfl_xor(lsA, 16); lsA += __shfl_xor(lsA, 32);
        lsB += __shfl_xor(lsB, 16); lsB += __shfl_xor(lsB, 32);
        l_iA += lsA; l_iB += lsB;

        #pragma unroll
        for (int j = 0; j < 4; ++j) {
            int off = (((2 * j + (lq >> 1)) ^ (l4 & 7)) << 3) + (lq & 1) * 4;
            ushort4 pA, pB;
            pA.x = f2bf_bits(stA[j][0]); pA.y = f2bf_bits(stA[j][1]);
            pA.z = f2bf_bits(stA[j][2]); pA.w = f2bf_bits(stA[j][3]);
            pB.x = f2bf_bits(stB[j][0]); pB.y = f2bf_bits(stB[j][1]);
            pB.z = f2bf_bits(stB[j][2]); pB.w = f2bf_bits(stB[j][3]);
            *(ushort4*)&PsA[off] = pA;
            *(ushort4*)&PsB[off] = pB;
        }
        bf16x8 paA0 = *(const bf16x8*)(PsA + sw0);
        bf16x8 paA1 = *(const bf16x8*)(PsA + sw1);
        bf16x8 paB0 = *(const bf16x8*)(PsB + sw0);
        bf16x8 paB1 = *(const bf16x8*)(PsB + sw1);

        #pragma unroll
        for (int j = 0; j < 4; ++j) {
            const __hip_bfloat16* vr = Vs + (16 * j + l4) * 64;
            bf16x8 vf0 = *(const bf16x8*)(vr + sw0);
            bf16x8 vf1 = *(const bf16x8*)(vr + sw1);
            oA[j] = __builtin_amdgcn_mfma_f32_16x16x32_bf16(paA0, vf0, oA[j], 0, 0, 0);
            oA[j] = __builtin_amdgcn_mfma_f32_16x16x32_bf16(paA1, vf1, oA[j], 0, 0, 0);
            oB[j] = __builtin_amdgcn_mfma_f32_16x16x32_bf16(paB0, vf0, oB[j], 0, 0, 0);
            oB[j] = __builtin_amdgcn_mfma_f32_16x16x32_bf16(paB1, vf1, oB[j], 0, 0, 0);
        }
    }

    size_t rb = (size_t)s * ROWS_PER_SPLIT + (size_t)(b * NHh + head) * HWl + qc * 128 + w * 32;
    #pragma unroll
    for (int j = 0; j < 4; ++j)
        #pragma unroll
        for (int r = 0; r < 4; ++r) {
            Opart[(rb + lq * 4 + r) * 64 + j * 16 + l4]      = oA[j][r];
            Opart[(rb + 16 + lq * 4 + r) * 64 + j * 16 + l4] = oB[j][r];
        }
    if (lq == 0) {
        lpart[rb + l4]      = l_iA;
        lpart[rb + 16 + l4] = l_iB;
    }
}

// =================== combine split partials ===================
__global__ void combine(const float* __restrict__ Opart, const float* __restrict__ lpart,
                        __hip_bfloat16* __restrict__ attn) {
    int p = blockIdx.x * 4 + (threadIdx.x >> 6);
    int d = threadIdx.x & 63;
    float L = 0.f, O = 0.f;
    #pragma unroll
    for (int s = 0; s < NSPL; ++s) {
        L += lpart[(size_t)s * ROWS_PER_SPLIT + p];
        O += Opart[((size_t)s * ROWS_PER_SPLIT + p) * 64 + d];
    }
    float res = O / L;
    int q = p & 1023;
    int bh = p >> 10;
    int head = bh % NHh, b = bh / NHh;
    attn[((size_t)(b * HWl + q)) * DINO + head * 64 + d] = __float2bfloat16(res);
}

// =================== launch ===================
extern "C" void kernel_launch(void* const* d_in, const int* in_sizes, int n_in,
                              void* d_out, int out_size, void* d_ws, size_t ws_size,
                              hipStream_t stream) {
    (void)in_sizes; (void)n_in; (void)out_size; (void)ws_size;
    const float* dino = (const float*)d_in[0];
    const float* cog  = (const float*)d_in[1];
    const float* tw   = (const float*)d_in[2];
    const float* Wq   = (const float*)d_in[3];
    const float* bq   = (const float*)d_in[4];
    const float* Wk   = (const float*)d_in[5];
    const float* bk   = (const float*)d_in[6];
    const float* Wv   = (const float*)d_in[7];
    const float* bv   = (const float*)d_in[8];
    const float* Wo   = (const float*)d_in[9];
    const float* bo   = (const float*)d_in[10];
    const float* gq   = (const float*)d_in[11];
    const float* Bq   = (const float*)d_in[12];
    const float* gkv  = (const float*)d_in[13];
    const float* Bkv  = (const float*)d_in[14];

    char* p = (char*)d_ws;
    float* xqT = (float*)p;                    p += (size_t)MQ * DINO * 4;
    __hip_bfloat16* xq = (__hip_bfloat16*)p;   p += (size_t)MQ * DINO * 2;
    char* alias = p;                           p += (size_t)MKV * COG * 2;   // xkv | Opart+lpart
    __hip_bfloat16* xkv = (__hip_bfloat16*)alias;
    __hip_bfloat16* WqT  = (__hip_bfloat16*)p; p += (size_t)DINO * DINO * 2;
    __hip_bfloat16* WkvT = (__hip_bfloat16*)p; p += (size_t)1536 * COG * 2;
    __hip_bfloat16* WoT  = (__hip_bfloat16*)p; p += (size_t)DINO * DINO * 2;
    __hip_bfloat16* qb   = (__hip_bfloat16*)p; p += (size_t)MQ  * DINO * 2;
    __hip_bfloat16* kb   = (__hip_bfloat16*)p; p += (size_t)MKV * DINO * 2;
    __hip_bfloat16* VT   = (__hip_bfloat16*)p; p += (size_t)MKV * DINO * 2;
    __hip_bfloat16* attnb = (__hip_bfloat16*)p; p += (size_t)MQ * DINO * 2;
    float* Opart = (float*)alias;
    float* lpart = (float*)(alias + (size_t)NSPL * ROWS_PER_SPLIT * 64 * 4);

    prep1<<<8192, 256, 0, stream>>>(dino, cog, gkv, Bkv,
                                    Wq, Wk, Wv, Wo, xqT, xkv, WqT, WkvT, WoT);
    prep2<<<MQ / 4, 256, 0, stream>>>(xqT, gq, Bq, xq);
    stage1<<<960, 256, 0, stream>>>(xq, WqT, bq, qb, xkv, WkvT, bk, bv, kb, VT);
    attn3<<<BB * NHh * 8 * NSPL, 256, 0, stream>>>(qb, kb, VT, tw, Opart, lpart);
    combine<<<ROWS_PER_SPLIT / 4, 256, 0, stream>>>(Opart, lpart, attnb);
    gemm_o<<<dim3(32, 6), 256, 0, stream>>>(attnb, WoT, bo, (float*)d_out);
}

// Round 9
// 274.980 us; speedup vs baseline: 1.3132x; 1.0137x over previous
//
#include <hip/hip_runtime.h>
#include <hip/hip_bf16.h>
#include <math.h>

#define BB   2
#define HWl  1024
#define DINO 768
#define COG  1920
#define NHh  12
#define TKV  4096
#define MQ   (BB*HWl)      // 2048
#define MKV  (BB*TKV)      // 8192
#define NSPL 4
#define ROWS_PER_SPLIT (BB*NHh*HWl)   // 24576

typedef __attribute__((ext_vector_type(8))) short bf16x8;
typedef __attribute__((ext_vector_type(4))) float f32x4;

__device__ __forceinline__ unsigned short f2bf_bits(float f) {
    __hip_bfloat16 h = __float2bfloat16(f);
    return *reinterpret_cast<unsigned short*>(&h);
}

__device__ __forceinline__ void glds16(const __hip_bfloat16* g, __hip_bfloat16* l) {
    __builtin_amdgcn_global_load_lds((const __attribute__((address_space(1))) void*)g,
                                     (__attribute__((address_space(3))) void*)l, 16, 0, 0);
}

// =================== prep1 mega-kernel ===================
// blocks [0,2048)     : LN of cog -> xkv bf16 (wave per row, 4 rows/block)
// blocks [2048,2432)  : dino NCHW -> xqT fp32 transpose (64x64 LDS tiles, coalesced)
// blocks [2432,8192)  : weight transposes -> WqT, WkvT(concat), WoT
__global__ __launch_bounds__(256) void prep1(const float* __restrict__ dino,
                                             const float* __restrict__ cog,
                                             const float* __restrict__ gkv, const float* __restrict__ Bkv,
                                             const float* __restrict__ Wq, const float* __restrict__ Wk,
                                             const float* __restrict__ Wv, const float* __restrict__ Wo,
                                             float* __restrict__ xqT,
                                             __hip_bfloat16* __restrict__ xkv,
                                             __hip_bfloat16* WqT, __hip_bfloat16* WkvT, __hip_bfloat16* WoT) {
    int bid = blockIdx.x, tid = threadIdx.x;
    if (bid < 2048) {
        const int W = COG, W4 = W >> 2, NC = 8;
        int row = bid * 4 + (tid >> 6), lane = tid & 63;
        const float4* xr = (const float4*)(cog + (size_t)row * W);
        const float4* g4 = (const float4*)gkv;
        const float4* b4 = (const float4*)Bkv;
        float4 v[NC];
        float s = 0.f, ss = 0.f;
        #pragma unroll
        for (int i = 0; i < NC; ++i) {
            int c = lane + i * 64;
            float4 t = (c < W4) ? xr[c] : (float4){0.f, 0.f, 0.f, 0.f};
            v[i] = t;
            s  += t.x + t.y + t.z + t.w;
            ss += t.x * t.x + t.y * t.y + t.z * t.z + t.w * t.w;
        }
        #pragma unroll
        for (int off = 1; off < 64; off <<= 1) {
            s  += __shfl_xor(s, off);
            ss += __shfl_xor(ss, off);
        }
        float mu = s / W;
        float rstd = rsqrtf(ss / W - mu * mu + 1e-5f);
        ushort4* yr = (ushort4*)(xkv + (size_t)row * W);
        #pragma unroll
        for (int i = 0; i < NC; ++i) {
            int c = lane + i * 64;
            if (c < W4) {
                float4 t = v[i];
                float4 gg = g4[c], bb = b4[c];
                ushort4 o;
                o.x = f2bf_bits((t.x - mu) * rstd * gg.x + bb.x);
                o.y = f2bf_bits((t.y - mu) * rstd * gg.y + bb.y);
                o.z = f2bf_bits((t.z - mu) * rstd * gg.z + bb.z);
                o.w = f2bf_bits((t.w - mu) * rstd * gg.w + bb.w);
                yr[c] = o;
            }
        }
    } else if (bid < 2432) {
        int t = bid - 2048;                 // 384 = 16 x 12 x 2
        int h0 = (t & 15) * 64;
        int c0 = ((t >> 4) % 12) * 64;
        int b = t / 192;
        __shared__ float T[64][65];
        #pragma unroll
        for (int i = 0; i < 16; ++i) {
            int idx = tid + i * 256;
            int c = idx >> 6, h = idx & 63;
            T[c][h] = dino[((size_t)b * DINO + c0 + c) * HWl + h0 + h];
        }
        __syncthreads();
        #pragma unroll
        for (int i = 0; i < 16; ++i) {
            int idx = tid + i * 256;
            int r = idx >> 6, c = idx & 63;
            xqT[((size_t)b * HWl + h0 + r) * DINO + c0 + c] = T[c][r];
        }
    } else {
        int bid2 = bid - 2432;
        int mid = bid2 / 1440, r = bid2 % 1440;
        int k0 = (r % 60) * 32, n0 = (r / 60) * 32;
        const float* src = (mid == 0) ? Wq : (mid == 1) ? Wk : (mid == 2) ? Wv : Wo;
        __hip_bfloat16* dst;
        int rowoff = 0;
        if (mid == 0) dst = WqT;
        else if (mid == 1) dst = WkvT;
        else if (mid == 2) { dst = WkvT; rowoff = 768; }
        else dst = WoT;
        int K = (mid == 1 || mid == 2) ? COG : DINO;
        if (k0 >= K) return;
        __shared__ float T[32][33];
        #pragma unroll
        for (int i = 0; i < 4; ++i) {
            int idx = tid + i * 256;
            int rr = idx >> 5, c = idx & 31;
            T[rr][c] = src[(size_t)(k0 + rr) * DINO + n0 + c];
        }
        __syncthreads();
        #pragma unroll
        for (int i = 0; i < 4; ++i) {
            int idx = tid + i * 256;
            int rr = idx >> 5, c = idx & 31;
            dst[(size_t)(rowoff + n0 + rr) * K + k0 + c] = __float2bfloat16(T[c][rr]);
        }
    }
}

// =================== prep2: LN of xqT rows -> xq bf16 ===================
__global__ __launch_bounds__(256) void prep2(const float* __restrict__ x,
                                             const float* __restrict__ g,
                                             const float* __restrict__ be,
                                             __hip_bfloat16* __restrict__ y) {
    const int W = DINO, NC = 3;
    int row = blockIdx.x * 4 + (threadIdx.x >> 6);
    int lane = threadIdx.x & 63;
    const float4* xr = (const float4*)(x + (size_t)row * W);
    const float4* g4 = (const float4*)g;
    const float4* b4 = (const float4*)be;
    float4 v[NC];
    float s = 0.f, ss = 0.f;
    #pragma unroll
    for (int i = 0; i < NC; ++i) {
        int c = lane + i * 64;
        float4 t = xr[c];
        v[i] = t;
        s  += t.x + t.y + t.z + t.w;
        ss += t.x * t.x + t.y * t.y + t.z * t.z + t.w * t.w;
    }
    #pragma unroll
    for (int off = 1; off < 64; off <<= 1) {
        s  += __shfl_xor(s, off);
        ss += __shfl_xor(ss, off);
    }
    float mu = s / W;
    float rstd = rsqrtf(ss / W - mu * mu + 1e-5f);
    ushort4* yr = (ushort4*)(y + (size_t)row * W);
    #pragma unroll
    for (int i = 0; i < NC; ++i) {
        int c = lane + i * 64;
        float4 t = v[i];
        float4 gg = g4[c], bb = b4[c];
        ushort4 o;
        o.x = f2bf_bits((t.x - mu) * rstd * gg.x + bb.x);
        o.y = f2bf_bits((t.y - mu) * rstd * gg.y + bb.y);
        o.z = f2bf_bits((t.z - mu) * rstd * gg.z + bb.z);
        o.w = f2bf_bits((t.w - mu) * rstd * gg.w + bb.w);
        yr[c] = o;
    }
}

// =================== stage1: fused Q GEMM + KV GEMM (Q blocks first) ===================
// blocks [0,192)   : Q:  xq[2048,768] @ WqT[768,768]^T -> qb
// blocks [192,960) : KV: xkv[8192,1920] @ WkvT[1536,1920]^T; n<768->kb, n>=768->VT
__global__ __launch_bounds__(256) void stage1(const __hip_bfloat16* __restrict__ xq,
                                              const __hip_bfloat16* __restrict__ WqT,
                                              const float* __restrict__ bq,
                                              __hip_bfloat16* __restrict__ qb,
                                              const __hip_bfloat16* __restrict__ xkv,
                                              const __hip_bfloat16* __restrict__ WkvT,
                                              const float* __restrict__ bk,
                                              const float* __restrict__ bv,
                                              __hip_bfloat16* __restrict__ kb,
                                              __hip_bfloat16* __restrict__ VT) {
    __shared__ __hip_bfloat16 SM[2 * 128 * 64];
    int bid = blockIdx.x;
    int tid = threadIdx.x, w = tid >> 6, lane = tid & 63;
    int l4 = lane & 15, lq = lane >> 4;
    int sws = l4 & 7;
    int rr = tid >> 3;
    int gcs = (tid & 7) ^ (rr & 7);

    if (bid >= 192) {
        const int K = COG;
        __hip_bfloat16* As = SM;
        __hip_bfloat16* Bs = SM + 128 * 64;
        int bidk = bid - 192;
        int m0 = (bidk & 63) * 128, n0 = (bidk >> 6) * 128;
        int mq = (w & 1) * 64, nq = (w >> 1) * 64;
        f32x4 acc[4][4];
        #pragma unroll
        for (int i = 0; i < 4; ++i)
            #pragma unroll
            for (int j = 0; j < 4; ++j) acc[i][j] = (f32x4){0.f, 0.f, 0.f, 0.f};

        const __hip_bfloat16* ag = xkv  + (size_t)(m0 + rr) * K + gcs * 8;
        const __hip_bfloat16* bg = WkvT + (size_t)(n0 + rr) * K + gcs * 8;
        __hip_bfloat16* asl = As + (w * 8) * 64;
        __hip_bfloat16* bsl = Bs + (w * 8) * 64;

        for (int k0 = 0; k0 < K; k0 += 64) {
            __syncthreads();
            #pragma unroll
            for (int g = 0; g < 4; ++g) {
                glds16(ag + (size_t)(g * 32) * K + k0, asl + g * 32 * 64);
                glds16(bg + (size_t)(g * 32) * K + k0, bsl + g * 32 * 64);
            }
            __syncthreads();
            #pragma unroll
            for (int h = 0; h < 2; ++h) {
                bf16x8 a[4], b[4];
                #pragma unroll
                for (int i = 0; i < 4; ++i)
                    a[i] = *(const bf16x8*)(As + (mq + 16 * i + l4) * 64 + (((h * 4 + lq) ^ sws) * 8));
                #pragma unroll
                for (int j = 0; j < 4; ++j)
                    b[j] = *(const bf16x8*)(Bs + (nq + 16 * j + l4) * 64 + (((h * 4 + lq) ^ sws) * 8));
                #pragma unroll
                for (int i = 0; i < 4; ++i)
                    #pragma unroll
                    for (int j = 0; j < 4; ++j)
                        acc[i][j] = __builtin_amdgcn_mfma_f32_16x16x32_bf16(a[i], b[j], acc[i][j], 0, 0, 0);
            }
        }

        if (n0 < 768) {
            #pragma unroll
            for (int i = 0; i < 4; ++i)
                #pragma unroll
                for (int j = 0; j < 4; ++j)
                    #pragma unroll
                    for (int r = 0; r < 4; ++r) {
                        int m = m0 + mq + 16 * i + lq * 4 + r;
                        int n = n0 + nq + 16 * j + l4;
                        kb[(size_t)m * DINO + n] = __float2bfloat16(acc[i][j][r] + bk[n]);
                    }
        } else {
            #pragma unroll
            for (int i = 0; i < 4; ++i)
                #pragma unroll
                for (int j = 0; j < 4; ++j)
                    #pragma unroll
                    for (int r = 0; r < 4; ++r) {
                        int m = m0 + mq + 16 * i + lq * 4 + r;
                        int n = n0 + nq + 16 * j + l4 - 768;
                        VT[((size_t)((m >> 12) * 768 + n)) * TKV + (m & 4095)] =
                            __float2bfloat16(acc[i][j][r] + bv[n]);
                    }
        }
    } else {
        const int K = DINO;
        __hip_bfloat16* As = SM;
        __hip_bfloat16* Bs = SM + 64 * 64;
        int m0 = (bid & 31) * 64, n0 = (bid >> 5) * 128;
        int mq = (w & 1) * 32, nq = (w >> 1) * 64;
        f32x4 acc[2][4];
        #pragma unroll
        for (int i = 0; i < 2; ++i)
            #pragma unroll
            for (int j = 0; j < 4; ++j) acc[i][j] = (f32x4){0.f, 0.f, 0.f, 0.f};

        const __hip_bfloat16* ag = xq  + (size_t)(m0 + rr) * K + gcs * 8;
        const __hip_bfloat16* bg = WqT + (size_t)(n0 + rr) * K + gcs * 8;
        __hip_bfloat16* asl = As + (w * 8) * 64;
        __hip_bfloat16* bsl = Bs + (w * 8) * 64;

        for (int k0 = 0; k0 < K; k0 += 64) {
            __syncthreads();
            #pragma unroll
            for (int g = 0; g < 2; ++g)
                glds16(ag + (size_t)(g * 32) * K + k0, asl + g * 32 * 64);
            #pragma unroll
            for (int g = 0; g < 4; ++g)
                glds16(bg + (size_t)(g * 32) * K + k0, bsl + g * 32 * 64);
            __syncthreads();
            #pragma unroll
            for (int h = 0; h < 2; ++h) {
                bf16x8 a[2], b[4];
                #pragma unroll
                for (int i = 0; i < 2; ++i)
                    a[i] = *(const bf16x8*)(As + (mq + 16 * i + l4) * 64 + (((h * 4 + lq) ^ sws) * 8));
                #pragma unroll
                for (int j = 0; j < 4; ++j)
                    b[j] = *(const bf16x8*)(Bs + (nq + 16 * j + l4) * 64 + (((h * 4 + lq) ^ sws) * 8));
                #pragma unroll
                for (int i = 0; i < 2; ++i)
                    #pragma unroll
                    for (int j = 0; j < 4; ++j)
                        acc[i][j] = __builtin_amdgcn_mfma_f32_16x16x32_bf16(a[i], b[j], acc[i][j], 0, 0, 0);
            }
        }
        #pragma unroll
        for (int i = 0; i < 2; ++i)
            #pragma unroll
            for (int j = 0; j < 4; ++j)
                #pragma unroll
                for (int r = 0; r < 4; ++r) {
                    int m = m0 + mq + 16 * i + lq * 4 + r;
                    int n = n0 + nq + 16 * j + l4;
                    qb[(size_t)m * DINO + n] = __float2bfloat16(acc[i][j][r] + bq[n]);
                }
    }
}

// =================== O projection: 64x64 tiles (C^T epilogue -> NCHW fp32) ===================
__global__ __launch_bounds__(256) void gemm_o(const __hip_bfloat16* __restrict__ A,
                                              const __hip_bfloat16* __restrict__ Bt,
                                              const float* __restrict__ bias,
                                              float* __restrict__ out) {
    const int K = DINO;
    __shared__ __hip_bfloat16 As[64 * 64];
    __shared__ __hip_bfloat16 Bs[64 * 64];
    int m0 = blockIdx.x * 64, n0 = blockIdx.y * 64;
    int tid = threadIdx.x, w = tid >> 6, lane = tid & 63;
    int l4 = lane & 15, lq = lane >> 4;
    int mq = (w & 1) * 32, nq = (w >> 1) * 32;
    f32x4 acc[2][2];
    #pragma unroll
    for (int i = 0; i < 2; ++i)
        #pragma unroll
        for (int j = 0; j < 2; ++j) acc[i][j] = (f32x4){0.f, 0.f, 0.f, 0.f};

    int rr = tid >> 3;
    int gc = (tid & 7) ^ (rr & 7);
    const __hip_bfloat16* ag = A  + (size_t)(m0 + rr) * K + gc * 8;
    const __hip_bfloat16* bg = Bt + (size_t)(n0 + rr) * K + gc * 8;
    __hip_bfloat16* asl = As + (w * 8) * 64;
    __hip_bfloat16* bsl = Bs + (w * 8) * 64;
    int sws = l4 & 7;

    for (int k0 = 0; k0 < K; k0 += 64) {
        __syncthreads();
        #pragma unroll
        for (int g = 0; g < 2; ++g) {
            glds16(ag + (size_t)(g * 32) * K + k0, asl + g * 32 * 64);
            glds16(bg + (size_t)(g * 32) * K + k0, bsl + g * 32 * 64);
        }
        __syncthreads();
        #pragma unroll
        for (int h = 0; h < 2; ++h) {
            bf16x8 a[2], b[2];
            #pragma unroll
            for (int i = 0; i < 2; ++i)
                a[i] = *(const bf16x8*)(As + (mq + 16 * i + l4) * 64 + (((h * 4 + lq) ^ sws) * 8));
            #pragma unroll
            for (int j = 0; j < 2; ++j)
                b[j] = *(const bf16x8*)(Bs + (nq + 16 * j + l4) * 64 + (((h * 4 + lq) ^ sws) * 8));
            #pragma unroll
            for (int i = 0; i < 2; ++i)
                #pragma unroll
                for (int j = 0; j < 2; ++j)
                    acc[i][j] = __builtin_amdgcn_mfma_f32_16x16x32_bf16(b[j], a[i], acc[i][j], 0, 0, 0);
        }
    }
    #pragma unroll
    for (int i = 0; i < 2; ++i)
        #pragma unroll
        for (int j = 0; j < 2; ++j)
            #pragma unroll
            for (int r = 0; r < 4; ++r) {
                int n = n0 + nq + 16 * j + lq * 4 + r;
                int m = m0 + mq + 16 * i + l4;
                int b = m >> 10, hw = m & 1023;
                out[((size_t)b * DINO + n) * HWl + hw] = acc[i][j][r] + bias[n];
            }
}

// =================== flash attention: 128-q tile, K/V double-buffered glds ===================
__global__ __launch_bounds__(256) void attn4(const __hip_bfloat16* __restrict__ qb,
                                             const __hip_bfloat16* __restrict__ kb,
                                             const __hip_bfloat16* __restrict__ VT,
                                             const float* __restrict__ tw,
                                             __hip_bfloat16* __restrict__ Opart,
                                             float* __restrict__ lpart) {
    int bid = blockIdx.x;
    int g = bid % 96, qc = bid / 96;
    int s = g & 3, bh = g >> 2;
    int head = bh % NHh, b = bh / NHh;
    int tid = threadIdx.x, w = tid >> 6, lane = tid & 63;
    int l4 = lane & 15, lq = lane >> 4;

    __shared__ __hip_bfloat16 Ks[2 * 64 * 64];
    __shared__ __hip_bfloat16 Vs[2 * 64 * 64];
    __shared__ __hip_bfloat16 Ps[4 * 32 * 64];

    const __hip_bfloat16* qbase = qb + (size_t)(b * HWl + qc * 128 + w * 32 + l4) * DINO + head * 64;
    bf16x8 qA0 = *(const bf16x8*)(qbase + lq * 8);
    bf16x8 qA1 = *(const bf16x8*)(qbase + 32 + lq * 8);
    const __hip_bfloat16* qbase2 = qbase + (size_t)16 * DINO;
    bf16x8 qB0 = *(const bf16x8*)(qbase2 + lq * 8);
    bf16x8 qB1 = *(const bf16x8*)(qbase2 + 32 + lq * 8);

    float c = tw[s] * 0.125f * 1.44269504f;
    float l_iA = 0.f, l_iB = 0.f;
    f32x4 oA[4], oB[4];
    #pragma unroll
    for (int j = 0; j < 4; ++j) { oA[j] = (f32x4){0.f,0.f,0.f,0.f}; oB[j] = (f32x4){0.f,0.f,0.f,0.f}; }

    int rowA = w * 16 + (lane >> 3);
    int cg = (lane & 7) ^ ((lane >> 3) & 7);
    const __hip_bfloat16* kg0 = kb + (size_t)(b * TKV + s * 1024 + rowA) * DINO + head * 64 + cg * 8;
    const __hip_bfloat16* kg1 = kg0 + (size_t)8 * DINO;
    const __hip_bfloat16* vg0 = VT + (size_t)(b * 768 + head * 64 + rowA) * TKV + s * 1024 + cg * 8;
    const __hip_bfloat16* vg1 = vg0 + (size_t)8 * TKV;
    int klo0 = (w * 2 + 0) * 512, klo1 = (w * 2 + 1) * 512;

    int sw0 = (lq ^ (l4 & 7)) * 8;
    int sw1 = ((4 + lq) ^ (l4 & 7)) * 8;
    __hip_bfloat16* PsA = Ps + w * 2048 + l4 * 64;
    __hip_bfloat16* PsB = Ps + w * 2048 + (16 + l4) * 64;

    // prologue: stage tile 0 into buffer 0
    glds16(kg0, Ks + klo0);
    glds16(kg1, Ks + klo1);
    glds16(vg0, Vs + klo0);
    glds16(vg1, Vs + klo1);

    for (int kt = 0; kt < 16; ++kt) {
        int cur = (kt & 1) * 4096;
        __syncthreads();   // drains pending glds (incl. prefetch of this tile)
        if (kt < 15) {
            int nxt = cur ^ 4096;
            glds16(kg0 + (size_t)(kt + 1) * 64 * DINO, Ks + nxt + klo0);
            glds16(kg1 + (size_t)(kt + 1) * 64 * DINO, Ks + nxt + klo1);
            glds16(vg0 + (kt + 1) * 64, Vs + nxt + klo0);
            glds16(vg1 + (kt + 1) * 64, Vs + nxt + klo1);
        }
        const __hip_bfloat16* Kc = Ks + cur;
        const __hip_bfloat16* Vc = Vs + cur;

        f32x4 stA[4], stB[4];
        #pragma unroll
        for (int j = 0; j < 4; ++j) {
            const __hip_bfloat16* kr = Kc + (16 * j + l4) * 64;
            bf16x8 kf0 = *(const bf16x8*)(kr + sw0);
            bf16x8 kf1 = *(const bf16x8*)(kr + sw1);
            f32x4 a = (f32x4){0.f,0.f,0.f,0.f};
            a = __builtin_amdgcn_mfma_f32_16x16x32_bf16(kf0, qA0, a, 0, 0, 0);
            a = __builtin_amdgcn_mfma_f32_16x16x32_bf16(kf1, qA1, a, 0, 0, 0);
            stA[j] = a;
            f32x4 bb = (f32x4){0.f,0.f,0.f,0.f};
            bb = __builtin_amdgcn_mfma_f32_16x16x32_bf16(kf0, qB0, bb, 0, 0, 0);
            bb = __builtin_amdgcn_mfma_f32_16x16x32_bf16(kf1, qB1, bb, 0, 0, 0);
            stB[j] = bb;
        }

        float lsA = 0.f, lsB = 0.f;
        #pragma unroll
        for (int j = 0; j < 4; ++j)
            #pragma unroll
            for (int r = 0; r < 4; ++r) {
                float eA = exp2f(stA[j][r] * c);
                float eB = exp2f(stB[j][r] * c);
                stA[j][r] = eA; lsA += eA;
                stB[j][r] = eB; lsB += eB;
            }
        lsA += __shfl_xor(lsA, 16); lsA += __shfl_xor(lsA, 32);
        lsB += __shfl_xor(lsB, 16); lsB += __shfl_xor(lsB, 32);
        l_iA += lsA; l_iB += lsB;

        #pragma unroll
        for (int j = 0; j < 4; ++j) {
            int off = (((2 * j + (lq >> 1)) ^ (l4 & 7)) << 3) + (lq & 1) * 4;
            ushort4 pA, pB;
            pA.x = f2bf_bits(stA[j][0]); pA.y = f2bf_bits(stA[j][1]);
            pA.z = f2bf_bits(stA[j][2]); pA.w = f2bf_bits(stA[j][3]);
            pB.x = f2bf_bits(stB[j][0]); pB.y = f2bf_bits(stB[j][1]);
            pB.z = f2bf_bits(stB[j][2]); pB.w = f2bf_bits(stB[j][3]);
            *(ushort4*)&PsA[off] = pA;
            *(ushort4*)&PsB[off] = pB;
        }
        bf16x8 paA0 = *(const bf16x8*)(PsA + sw0);
        bf16x8 paA1 = *(const bf16x8*)(PsA + sw1);
        bf16x8 paB0 = *(const bf16x8*)(PsB + sw0);
        bf16x8 paB1 = *(const bf16x8*)(PsB + sw1);

        #pragma unroll
        for (int j = 0; j < 4; ++j) {
            const __hip_bfloat16* vr = Vc + (16 * j + l4) * 64;
            bf16x8 vf0 = *(const bf16x8*)(vr + sw0);
            bf16x8 vf1 = *(const bf16x8*)(vr + sw1);
            oA[j] = __builtin_amdgcn_mfma_f32_16x16x32_bf16(paA0, vf0, oA[j], 0, 0, 0);
            oA[j] = __builtin_amdgcn_mfma_f32_16x16x32_bf16(paA1, vf1, oA[j], 0, 0, 0);
            oB[j] = __builtin_amdgcn_mfma_f32_16x16x32_bf16(paB0, vf0, oB[j], 0, 0, 0);
            oB[j] = __builtin_amdgcn_mfma_f32_16x16x32_bf16(paB1, vf1, oB[j], 0, 0, 0);
        }
    }

    size_t rb = (size_t)s * ROWS_PER_SPLIT + (size_t)(b * NHh + head) * HWl + qc * 128 + w * 32;
    #pragma unroll
    for (int j = 0; j < 4; ++j)
        #pragma unroll
        for (int r = 0; r < 4; ++r) {
            Opart[(rb + lq * 4 + r) * 64 + j * 16 + l4]      = __float2bfloat16(oA[j][r]);
            Opart[(rb + 16 + lq * 4 + r) * 64 + j * 16 + l4] = __float2bfloat16(oB[j][r]);
        }
    if (lq == 0) {
        lpart[rb + l4]      = l_iA;
        lpart[rb + 16 + l4] = l_iB;
    }
}

// =================== combine split partials ===================
__global__ void combine(const __hip_bfloat16* __restrict__ Opart, const float* __restrict__ lpart,
                        __hip_bfloat16* __restrict__ attn) {
    int p = blockIdx.x * 4 + (threadIdx.x >> 6);
    int d = threadIdx.x & 63;
    float L = 0.f, O = 0.f;
    #pragma unroll
    for (int s = 0; s < NSPL; ++s) {
        L += lpart[(size_t)s * ROWS_PER_SPLIT + p];
        O += __bfloat162float(Opart[((size_t)s * ROWS_PER_SPLIT + p) * 64 + d]);
    }
    float res = O / L;
    int q = p & 1023;
    int bh = p >> 10;
    int head = bh % NHh, b = bh / NHh;
    attn[((size_t)(b * HWl + q)) * DINO + head * 64 + d] = __float2bfloat16(res);
}

// =================== launch ===================
extern "C" void kernel_launch(void* const* d_in, const int* in_sizes, int n_in,
                              void* d_out, int out_size, void* d_ws, size_t ws_size,
                              hipStream_t stream) {
    (void)in_sizes; (void)n_in; (void)out_size; (void)ws_size;
    const float* dino = (const float*)d_in[0];
    const float* cog  = (const float*)d_in[1];
    const float* tw   = (const float*)d_in[2];
    const float* Wq   = (const float*)d_in[3];
    const float* bq   = (const float*)d_in[4];
    const float* Wk   = (const float*)d_in[5];
    const float* bk   = (const float*)d_in[6];
    const float* Wv   = (const float*)d_in[7];
    const float* bv   = (const float*)d_in[8];
    const float* Wo   = (const float*)d_in[9];
    const float* bo   = (const float*)d_in[10];
    const float* gq   = (const float*)d_in[11];
    const float* Bq   = (const float*)d_in[12];
    const float* gkv  = (const float*)d_in[13];
    const float* Bkv  = (const float*)d_in[14];

    char* p = (char*)d_ws;
    float* xqT = (float*)p;                    p += (size_t)MQ * DINO * 4;
    __hip_bfloat16* xq = (__hip_bfloat16*)p;   p += (size_t)MQ * DINO * 2;
    char* alias = p;                           p += (size_t)MKV * COG * 2;   // xkv | Opart+lpart
    __hip_bfloat16* xkv = (__hip_bfloat16*)alias;
    __hip_bfloat16* WqT  = (__hip_bfloat16*)p; p += (size_t)DINO * DINO * 2;
    __hip_bfloat16* WkvT = (__hip_bfloat16*)p; p += (size_t)1536 * COG * 2;
    __hip_bfloat16* WoT  = (__hip_bfloat16*)p; p += (size_t)DINO * DINO * 2;
    __hip_bfloat16* qb   = (__hip_bfloat16*)p; p += (size_t)MQ  * DINO * 2;
    __hip_bfloat16* kb   = (__hip_bfloat16*)p; p += (size_t)MKV * DINO * 2;
    __hip_bfloat16* VT   = (__hip_bfloat16*)p; p += (size_t)MKV * DINO * 2;
    __hip_bfloat16* attnb = (__hip_bfloat16*)p; p += (size_t)MQ * DINO * 2;
    __hip_bfloat16* Opart = (__hip_bfloat16*)alias;
    float* lpart = (float*)(alias + (size_t)NSPL * ROWS_PER_SPLIT * 64 * 2);

    prep1<<<8192, 256, 0, stream>>>(dino, cog, gkv, Bkv,
                                    Wq, Wk, Wv, Wo, xqT, xkv, WqT, WkvT, WoT);
    prep2<<<MQ / 4, 256, 0, stream>>>(xqT, gq, Bq, xq);
    stage1<<<960, 256, 0, stream>>>(xq, WqT, bq, qb, xkv, WkvT, bk, bv, kb, VT);
    attn4<<<BB * NHh * 8 * NSPL, 256, 0, stream>>>(qb, kb, VT, tw, Opart, lpart);
    combine<<<ROWS_PER_SPLIT / 4, 256, 0, stream>>>(Opart, lpart, attnb);
    gemm_o<<<dim3(32, 12), 256, 0, stream>>>(attnb, WoT, bo, (float*)d_out);
}